// Round 17
// baseline (439.790 us; speedup 1.0000x reference)
//
#include <hip/hip_runtime.h>
#include <hip/hip_bf16.h>

typedef float f32x4 __attribute__((ext_vector_type(4)));
typedef _Float16 half8 __attribute__((ext_vector_type(8)));
typedef _Float16 half4 __attribute__((ext_vector_type(4)));

__device__ __forceinline__ unsigned short f2h(float f) {
  return __builtin_bit_cast(unsigned short, (_Float16)f);   // RNE
}
__device__ __forceinline__ float h2f(unsigned short u) {
  return (float)__builtin_bit_cast(_Float16, u);
}
// expand low 2 bits -> packed pair of fp16 {1.0|0.0}  (bit-exact, integer mul)
__device__ __forceinline__ unsigned expand2(unsigned b2) {
  return ((b2 & 1u) | ((b2 & 2u) << 15)) * 0x3C00u;
}
// expand 8 bits -> 8 fp16 {1.0|0.0}
__device__ __forceinline__ half8 expand8(unsigned v) {
  uint4 u;
  u.x = expand2(v);
  u.y = expand2(v >> 2);
  u.z = expand2(v >> 4);
  u.w = expand2(v >> 6);
  return __builtin_bit_cast(half8, u);
}

// ---- pack adj -> bit-packed transposed Abits[b][i][j/32] + type counts.
//      Register bit-build: no input LDS tile, no barriers in main loop.
//      blocks >= 1024 do the weight transpose. ----
__global__ __launch_bounds__(256) void k_pack(const int* __restrict__ adj,
    unsigned* __restrict__ Abits, float* __restrict__ cnt,
    const float* __restrict__ w0b, const float* __restrict__ w1a,
    const float* __restrict__ w1b, const float* __restrict__ w2a,
    const float* __restrict__ w2b, unsigned short* __restrict__ wT) {
  __shared__ unsigned bitT[128 * 33];  // 16.9 KB
  __shared__ float cred[256 * 3];      // 3 KB
  int blk = blockIdx.x;
  if (blk >= 1024) {                   // weight transpose: 640 blocks
    int wb = blk - 1024;
    if (threadIdx.x < 128) {
      int mat = wb >> 7, k = wb & 127, dd = threadIdx.x;
      const float* src = (mat == 0) ? w0b : (mat == 1) ? w1a : (mat == 2) ? w1b
                        : (mat == 3) ? w2a : w2b;
      wT[mat * 16384 + dd * 128 + k] = f2h(src[k * 128 + dd]);
    }
    return;
  }
  int b = blk >> 3, i0 = (blk & 7) << 7;
  int t = threadIdx.x;
  int g = t >> 6;                      // wave id: one jt per wave per outer iter
  int u = t & 63, iq = u & 31, js = u >> 5;
  for (int o = 0; o < 4; ++o) {
    int jt = o * 4 + g;
    int jbase = jt << 6;
    unsigned b0 = 0, b1 = 0, b2 = 0, b3 = 0;
    for (int r = 0; r < 32; ++r) {
      int jl = js * 32 + r;
      int4 v = *reinterpret_cast<const int4*>(
          &adj[((size_t)b << 20) + ((size_t)(jbase + jl) << 10) + i0 + iq * 4]);
      b0 |= (unsigned)(v.x & 1) << r;
      b1 |= (unsigned)(v.y & 1) << r;
      b2 |= (unsigned)(v.z & 1) << r;
      b3 |= (unsigned)(v.w & 1) << r;
    }
    int base = (iq * 4) * 33 + jt * 2 + js;
    bitT[base] = b0;
    bitT[base + 33] = b1;
    bitT[base + 66] = b2;
    bitT[base + 99] = b3;
  }
  __syncthreads();
  // counts from bitT (bit-identical integers to direct counting)
  {
    int il = t & 127, half = t >> 7;
    float c0 = 0, c1 = 0, c2 = 0;
    for (int mi = 0; mi < 16; ++mi) {
      int m = half * 16 + mi;          // word index 0..31; jt = m>>1
      int pc = __popc(bitT[il * 33 + m]);
      if (half == 0) c0 += pc;         // m<16  -> j<512   (type 0)
      else if (m < 24) c1 += pc;       // jt 8..11 -> type 1
      else c2 += pc;                   // jt 12..15 -> type 2
    }
    cred[t * 3 + 0] = c0;
    cred[t * 3 + 1] = c1;
    cred[t * 3 + 2] = c2;
  }
  __syncthreads();
  if (t < 128) {
    for (int c = 0; c < 3; ++c)
      cnt[(((size_t)b << 10) + i0 + t) * 4 + c] = cred[t * 3 + c] + cred[(t + 128) * 3 + c];
  }
  unsigned* dst = Abits + ((size_t)b << 15) + ((size_t)i0 << 5);
  for (int q = 0; q < 16; ++q) {
    int f = t + 256 * q;
    dst[f] = bitT[(f >> 5) * 33 + (f & 31)];
  }
}

// ---- fused layer (layers 1,2): agg=h+A^T h -> z=leaky(agg@wa+ba) -> m=z@wb+bb
//      + BN partial stats. Residual from h_t (L2-hot). XCD-swizzled blockIdx. ----
__global__ __launch_bounds__(256) void k_layer(const unsigned* __restrict__ Abits,
    const unsigned short* __restrict__ h_t,
    const unsigned short* __restrict__ waT, const float* __restrict__ ba,
    const unsigned short* __restrict__ wbT, const float* __restrict__ bb,
    unsigned short* __restrict__ m_out, float* __restrict__ ps, float* __restrict__ pq) {
  __shared__ __align__(16) unsigned short smem[18432];   // 36.9 KB
  unsigned short* tb0 = smem;           // phase A: h_t tile buf0 [128][72]
  unsigned short* tb1 = smem + 9216;    // phase A: h_t tile buf1
  unsigned short* tz = smem;            // phase B: agg/z/m [128][136]
  int d = blockIdx.x;
  // XCD swizzle: all 8 subtiles of a graph land on the same XCD (bijective)
  int b = (d & 7) + ((d >> 6) << 3);
  int i0 = ((d >> 3) & 7) << 7;
  int t = threadIdx.x;
  int w = t >> 6, lane = t & 63;
  int wr = (w >> 1) * 64, wc = (w & 1) * 64;
  int lr = lane & 15, lk8 = (lane >> 4) * 8;
  const unsigned* Ab = Abits + ((size_t)b << 15);

  // ---- phase A: SpMM (A^T h), A from bit-expansion in registers ----
  f32x4 acc[4][4] = {};
  {
    for (int q = 0; q < 4; ++q) {
      int c = t * 4 + q;
      int r = c >> 3, off = (c & 7) << 3;
      *reinterpret_cast<uint4*>(&tb0[r * 72 + off]) =
        *reinterpret_cast<const uint4*>(&h_t[(((size_t)b << 7) + r) * 1024 + off]);
    }
  }
  __syncthreads();
  for (int jt = 0; jt < 16; ++jt) {
    unsigned short* cur = (jt & 1) ? tb1 : tb0;
    unsigned short* nxt = (jt & 1) ? tb0 : tb1;
    if (jt < 15) {
      for (int q = 0; q < 4; ++q) {
        int c = t * 4 + q;
        int r = c >> 3, off = (c & 7) << 3;
        *reinterpret_cast<uint4*>(&nxt[r * 72 + off]) =
          *reinterpret_cast<const uint4*>(&h_t[(((size_t)b << 7) + r) * 1024 + ((jt + 1) << 6) + off]);
      }
    }
    uint2 w01[4];
#pragma unroll
    for (int x = 0; x < 4; ++x)
      w01[x] = *reinterpret_cast<const uint2*>(&Ab[(i0 + wr + x * 16 + lr) * 32 + jt * 2]);
#pragma unroll
    for (int ks = 0; ks < 2; ++ks) {
      half8 bfr[4];
#pragma unroll
      for (int x = 0; x < 4; ++x)
        bfr[x] = *reinterpret_cast<const half8*>(&cur[(wc + x * 16 + lr) * 72 + ks * 32 + lk8]);
      half8 af[4];
#pragma unroll
      for (int x = 0; x < 4; ++x) {
        unsigned wk = ks ? w01[x].y : w01[x].x;
        af[x] = expand8(wk >> lk8);
      }
#pragma unroll
      for (int x = 0; x < 4; ++x)
#pragma unroll
        for (int y = 0; y < 4; ++y)
          acc[x][y] = __builtin_amdgcn_mfma_f32_16x16x32_f16(af[x], bfr[y], acc[x][y], 0, 0, 0);
    }
    __syncthreads();
  }
  // ---- residual add (from h_t, q-rows contiguous), agg -> tz (fp16) ----
  for (int x = 0; x < 4; ++x)
    for (int y = 0; y < 4; ++y) {
      int col = wc + y * 16 + lr;
      int row0 = wr + x * 16 + ((lane >> 4) << 2);
      uint2 rbits = *reinterpret_cast<const uint2*>(
          &h_t[((size_t)(b * 128 + col)) * 1024 + i0 + row0]);
      half4 rh = __builtin_bit_cast(half4, rbits);
      for (int q = 0; q < 4; ++q)
        tz[(row0 + q) * 136 + col] = f2h(acc[x][y][q] + (float)rh[q]);
    }
  __syncthreads();
  // ---- GEMM1: z = leaky(agg @ waT' + ba), weights direct from global ----
  f32x4 acc2[4][4] = {};
#pragma unroll
  for (int kt = 0; kt < 2; ++kt)
#pragma unroll
    for (int ks = 0; ks < 2; ++ks) {
      int k0 = kt * 64 + ks * 32 + lk8;
      half8 af[4], bw[4];
#pragma unroll
      for (int x = 0; x < 4; ++x)
        af[x] = *reinterpret_cast<const half8*>(&tz[(wr + x * 16 + lr) * 136 + k0]);
#pragma unroll
      for (int x = 0; x < 4; ++x)
        bw[x] = *reinterpret_cast<const half8*>(&waT[(wc + x * 16 + lr) * 128 + k0]);
#pragma unroll
      for (int x = 0; x < 4; ++x)
#pragma unroll
        for (int y = 0; y < 4; ++y)
          acc2[x][y] = __builtin_amdgcn_mfma_f32_16x16x32_f16(af[x], bw[y], acc2[x][y], 0, 0, 0);
    }
  __syncthreads();   // all GEMM1 tz reads done
  for (int x = 0; x < 4; ++x)
    for (int y = 0; y < 4; ++y)
      for (int q = 0; q < 4; ++q) {
        int row = wr + x * 16 + ((lane >> 4) << 2) + q;
        int col = wc + y * 16 + lr;
        float vv = acc2[x][y][q] + ba[col];
        vv = vv > 0.f ? vv : 0.1f * vv;
        tz[row * 136 + col] = f2h(vv);
      }
  __syncthreads();
  // ---- GEMM2: m = z @ wbT' + bb ----
  f32x4 acc3[4][4] = {};
#pragma unroll
  for (int kt = 0; kt < 2; ++kt)
#pragma unroll
    for (int ks = 0; ks < 2; ++ks) {
      int k0 = kt * 64 + ks * 32 + lk8;
      half8 af[4], bw[4];
#pragma unroll
      for (int x = 0; x < 4; ++x)
        af[x] = *reinterpret_cast<const half8*>(&tz[(wr + x * 16 + lr) * 136 + k0]);
#pragma unroll
      for (int x = 0; x < 4; ++x)
        bw[x] = *reinterpret_cast<const half8*>(&wbT[(wc + x * 16 + lr) * 128 + k0]);
#pragma unroll
      for (int x = 0; x < 4; ++x)
#pragma unroll
        for (int y = 0; y < 4; ++y)
          acc3[x][y] = __builtin_amdgcn_mfma_f32_16x16x32_f16(af[x], bw[y], acc3[x][y], 0, 0, 0);
    }
  __syncthreads();   // GEMM2's tz reads done before tz overwrite
  // ---- epilogue: m -> tz (fp16, same bits) + BN partial stats (f32) ----
  float s[4] = {}, q2[4] = {};
  for (int x = 0; x < 4; ++x)
    for (int y = 0; y < 4; ++y)
      for (int q = 0; q < 4; ++q) {
        int row = wr + x * 16 + ((lane >> 4) << 2) + q;
        int col = wc + y * 16 + lr;
        float vv = acc3[x][y][q] + bb[col];
        tz[row * 136 + col] = f2h(vv);
        s[y] += vv; q2[y] += vv * vv;
      }
  __syncthreads();   // m tile complete in tz
  // coalesced vector store of m (row-major), 8x uint4 per thread
  {
    int r2 = t >> 1, hf2 = t & 1;
    size_t mbase = (((size_t)b << 10) + i0 + r2) * 128 + hf2 * 64;
#pragma unroll
    for (int j = 0; j < 8; ++j)
      *reinterpret_cast<uint4*>(&m_out[mbase + j * 8]) =
        *reinterpret_cast<const uint4*>(&tz[r2 * 136 + hf2 * 64 + j * 8]);
  }
  __syncthreads();   // tz reads done before smem reuse as float
  float* fs = (float*)smem;          // [128][8]
  float* fq = fs + 1024;             // [128][8]
  int slot = (w >> 1) * 4 + (lane >> 4);
  for (int y = 0; y < 4; ++y) {
    int col = wc + y * 16 + lr;
    fs[col * 8 + slot] = s[y];
    fq[col * 8 + slot] = q2[y];
  }
  __syncthreads();
  if (t < 128) {
    float S = 0, Q = 0;
    for (int k = 0; k < 8; ++k) { S += fs[t * 8 + k]; Q += fq[t * 8 + k]; }
    ps[d * 128 + t] = S;
    pq[d * 128 + t] = Q;
  }
}

// ---- fused layer 0: z0 closed-form from counts -> m = z0 @ w0bT' + b0b + stats ----
__global__ __launch_bounds__(256) void k_layer0(const float* __restrict__ cnt,
    const float* __restrict__ w0a, const float* __restrict__ b0a,
    const float* __restrict__ g3, const float* __restrict__ bb3,
    const unsigned short* __restrict__ wbT, const float* __restrict__ bb,
    unsigned short* __restrict__ m_out, float* __restrict__ ps, float* __restrict__ pq) {
  __shared__ __align__(16) unsigned short smem[17408];
  unsigned short* tz = smem;            // [128][136]
  int blk = blockIdx.x;
  int b = blk >> 3, i0 = (blk & 7) << 7;
  int t = threadIdx.x;
  int w = t >> 6, lane = t & 63;
  int wr = (w >> 1) * 64, wc = (w & 1) * 64;
  int lr = lane & 15, lk8 = (lane >> 4) * 8;

  const float mean3[3] = {0.5f, 0.25f, 0.25f};
  const float var3[3] = {0.25f, 0.1875f, 0.1875f};
  float v[3][3];
  for (int c = 0; c < 3; ++c) {
    float rs = rsqrtf(var3[c] + 1e-5f) * g3[c];
    for (int tt = 0; tt < 3; ++tt)
      v[tt][c] = ((tt == c ? 1.f : 0.f) - mean3[c]) * rs + bb3[c];
  }
  int rr = t >> 1, hf = t & 1;
  int i = i0 + rr;
  int ty = i < 512 ? 0 : (i < 768 ? 1 : 2);
  const float* cc = cnt + (((size_t)b << 10) + i) * 4;
  float a0 = v[ty][0] + cc[0] * v[0][0] + cc[1] * v[1][0] + cc[2] * v[2][0];
  float a1 = v[ty][1] + cc[0] * v[0][1] + cc[1] * v[1][1] + cc[2] * v[2][1];
  float a2 = v[ty][2] + cc[0] * v[0][2] + cc[1] * v[1][2] + cc[2] * v[2][2];
  for (int c = 0; c < 64; ++c) {
    int col = hf * 64 + c;
    float z = a0 * w0a[col] + a1 * w0a[128 + col] + a2 * w0a[256 + col] + b0a[col];
    tz[rr * 136 + col] = f2h(fmaxf(z, 0.f));
  }
  __syncthreads();
  f32x4 acc3[4][4] = {};
#pragma unroll
  for (int kt = 0; kt < 2; ++kt)
#pragma unroll
    for (int ks = 0; ks < 2; ++ks) {
      int k0 = kt * 64 + ks * 32 + lk8;
      half8 af[4], bw[4];
#pragma unroll
      for (int x = 0; x < 4; ++x)
        af[x] = *reinterpret_cast<const half8*>(&tz[(wr + x * 16 + lr) * 136 + k0]);
#pragma unroll
      for (int x = 0; x < 4; ++x)
        bw[x] = *reinterpret_cast<const half8*>(&wbT[(wc + x * 16 + lr) * 128 + k0]);
#pragma unroll
      for (int x = 0; x < 4; ++x)
#pragma unroll
        for (int y = 0; y < 4; ++y)
          acc3[x][y] = __builtin_amdgcn_mfma_f32_16x16x32_f16(af[x], bw[y], acc3[x][y], 0, 0, 0);
    }
  __syncthreads();   // GEMM's tz reads done before tz overwrite
  float s[4] = {}, q2[4] = {};
  for (int x = 0; x < 4; ++x)
    for (int y = 0; y < 4; ++y)
      for (int q = 0; q < 4; ++q) {
        int row = wr + x * 16 + ((lane >> 4) << 2) + q;
        int col = wc + y * 16 + lr;
        float vv = acc3[x][y][q] + bb[col];
        tz[row * 136 + col] = f2h(vv);
        s[y] += vv; q2[y] += vv * vv;
      }
  __syncthreads();   // m tile complete in tz
  {
    int r2 = t >> 1, hf2 = t & 1;
    size_t mbase = (((size_t)b << 10) + i0 + r2) * 128 + hf2 * 64;
#pragma unroll
    for (int j = 0; j < 8; ++j)
      *reinterpret_cast<uint4*>(&m_out[mbase + j * 8]) =
        *reinterpret_cast<const uint4*>(&tz[r2 * 136 + hf2 * 64 + j * 8]);
  }
  __syncthreads();   // tz reads done before smem reuse as float
  float* fs = (float*)smem;
  float* fq = fs + 1024;
  int slot = (w >> 1) * 4 + (lane >> 4);
  for (int y = 0; y < 4; ++y) {
    int col = wc + y * 16 + lr;
    fs[col * 8 + slot] = s[y];
    fq[col * 8 + slot] = q2[y];
  }
  __syncthreads();
  if (t < 128) {
    float S = 0, Q = 0;
    for (int k = 0; k < 8; ++k) { S += fs[t * 8 + k]; Q += fq[t * 8 + k]; }
    ps[blk * 128 + t] = S;
    pq[blk * 128 + t] = Q;
  }
}

// ---- BN stats final reduce: 128 blocks (one per channel) ----
__global__ __launch_bounds__(256) void k_bnred(const float* __restrict__ ps,
    const float* __restrict__ pq, const float* __restrict__ g,
    const float* __restrict__ be, float* __restrict__ st) {
  __shared__ float rs[4], rq[4];
  int ch = blockIdx.x, t = threadIdx.x;
  float s = 0, q = 0;
  for (int k = t; k < 1024; k += 256) {
    s += ps[k * 128 + ch]; q += pq[k * 128 + ch];
  }
  for (int off = 32; off; off >>= 1) {
    s += __shfl_down(s, off); q += __shfl_down(q, off);
  }
  if ((t & 63) == 0) { rs[t >> 6] = s; rq[t >> 6] = q; }
  __syncthreads();
  if (t == 0) {
    s = rs[0] + rs[1] + rs[2] + rs[3];
    q = rq[0] + rq[1] + rq[2] + rq[3];
    float mean = s * (1.f / 131072.f);
    float var = q * (1.f / 131072.f) - mean * mean;
    float sc = g[ch] * rsqrtf(var + 1e-5f);
    st[ch * 2] = sc;
    st[ch * 2 + 1] = be[ch] - mean * sc;
  }
}

// ---- BN apply + relu + residual; h row-major + transposed; optional pool partials ----
__global__ __launch_bounds__(256) void k_apply(const unsigned short* __restrict__ m,
    const float* __restrict__ st, unsigned short* __restrict__ h_rm,
    unsigned short* __restrict__ h_t, float* __restrict__ pool_ps,
    int use_res, int write_t, int do_pool) {
  __shared__ unsigned short lt[128 * 131];   // 33.5 KB (131: 2-way max bank alias)
  __shared__ float lp[128 * 16];             // 8 KB
  int blk = blockIdx.x;
  int b = blk >> 3, i0 = (blk & 7) << 7;
  int t = threadIdx.x;
  int chg = t & 15, rowg = t >> 4;
  int ch0 = chg * 8;
  float sc[8], sh[8];
#pragma unroll
  for (int j = 0; j < 8; ++j) { sc[j] = st[(ch0 + j) * 2]; sh[j] = st[(ch0 + j) * 2 + 1]; }
  float psum[8] = {};
  for (int it = 0; it < 8; ++it) {
    int row = it * 16 + rowg;
    size_t base = ((((size_t)b << 10) + i0 + row) << 7) + ch0;
    half8 mv = *reinterpret_cast<const half8*>(&m[base]);
    half8 rv{};
    if (use_res) rv = *reinterpret_cast<const half8*>(&h_rm[base]);
    half8 out;
#pragma unroll
    for (int j = 0; j < 8; ++j) {
      float vv = (float)mv[j] * sc[j] + sh[j];
      if (use_res) vv += (float)rv[j];
      vv = fmaxf(vv, 0.f);
      _Float16 hv = (_Float16)vv;
      out[j] = hv;
      psum[j] += (float)hv;
      lt[(ch0 + j) * 131 + row] = __builtin_bit_cast(unsigned short, hv);
    }
    if (write_t)   // h_rm only needed as next layer's residual source
      *reinterpret_cast<half8*>(&h_rm[base]) = out;
  }
  if (write_t) {
    __syncthreads();
    for (int it = 0; it < 16; ++it) {
      int ch2 = it * 8 + (t >> 5);
      int pu = (t & 31) * 4;
      unsigned u0 = lt[ch2 * 131 + pu];
      unsigned u1 = lt[ch2 * 131 + pu + 1];
      unsigned u2 = lt[ch2 * 131 + pu + 2];
      unsigned u3 = lt[ch2 * 131 + pu + 3];
      uint2 vv; vv.x = u0 | (u1 << 16); vv.y = u2 | (u3 << 16);
      *reinterpret_cast<uint2*>(&h_t[(((size_t)b << 7) + ch2) * 1024 + i0 + pu]) = vv;
    }
  }
  if (do_pool) {
#pragma unroll
    for (int j = 0; j < 8; ++j) lp[(ch0 + j) * 16 + rowg] = psum[j];
    __syncthreads();
    if (t < 128) {
      float S = 0;
      for (int k = 0; k < 16; ++k) S += lp[t * 16 + k];
      pool_ps[blk * 128 + t] = S;
    }
  }
}

// ---- pool merge + LayerNorm + fc1, fused (block = one graph) ----
__global__ __launch_bounds__(256) void k_poolfc1(const float* __restrict__ pool_ps,
    const float* __restrict__ ln_g, const float* __restrict__ ln_b,
    const float* __restrict__ w, const float* __restrict__ bias,
    float* __restrict__ y1) {
  __shared__ float ln[128];
  __shared__ float stat[2];
  int b = blockIdx.x, t = threadIdx.x;
  if (t < 128) {
    float s = 0;
    for (int k = 0; k < 8; ++k) s += pool_ps[((b << 3) + k) * 128 + t];
    ln[t] = s * (1.f / 1024.f);
  }
  __syncthreads();
  if (t < 64) {
    float a = ln[t], c = ln[t + 64];
    float ss = a + c, qq = a * a + c * c;
    for (int off = 32; off; off >>= 1) { ss += __shfl_down(ss, off); qq += __shfl_down(qq, off); }
    if (t == 0) {
      float mean = ss * (1.f / 128.f);
      float var = qq * (1.f / 128.f) - mean * mean;
      stat[0] = mean; stat[1] = rsqrtf(var + 1e-5f);
    }
  }
  __syncthreads();
  if (t < 128) ln[t] = (ln[t] - stat[0]) * stat[1] * ln_g[t] + ln_b[t];
  __syncthreads();
  float s = bias[t];
  for (int k = 0; k < 128; ++k) s += ln[k] * w[k * 256 + t];
  y1[b * 256 + t] = s;
}

// ---- bnhead1 + fc2 fused: each block recomputes stats (identical serial order) ----
__global__ __launch_bounds__(512) void k_fc2bn(const float* __restrict__ y1,
    const float* __restrict__ g, const float* __restrict__ be,
    const float* __restrict__ w, const float* __restrict__ bias,
    float* __restrict__ y2) {
  __shared__ float z1s[256];
  int b = blockIdx.x, t = threadIdx.x;
  if (t < 256) {
    float s = 0, q = 0;
    for (int bb = 0; bb < 128; ++bb) { float v = y1[bb * 256 + t]; s += v; q += v * v; }
    float mean = s * (1.f / 128.f);
    float var = q * (1.f / 128.f) - mean * mean;
    float sc = g[t] * rsqrtf(var + 1e-5f);
    float sh = be[t] - mean * sc;
    float v = y1[b * 256 + t] * sc + sh;
    z1s[t] = v > 0.f ? v : 0.1f * v;
  }
  __syncthreads();
  float s = bias[t];
  for (int k = 0; k < 256; ++k) s += z1s[k] * w[k * 512 + t];
  y2[b * 512 + t] = s;
}

// ---- bnhead2 + fc3 fused ----
__global__ __launch_bounds__(512) void k_fc3bn(const float* __restrict__ y2,
    const float* __restrict__ g, const float* __restrict__ be,
    const float* __restrict__ w, const float* __restrict__ bias,
    float* __restrict__ out) {
  __shared__ float red[512];
  int b = blockIdx.x, t = threadIdx.x;
  float s = 0, q = 0;
  for (int bb = 0; bb < 128; ++bb) { float v = y2[bb * 512 + t]; s += v; q += v * v; }
  float mean = s * (1.f / 128.f);
  float var = q * (1.f / 128.f) - mean * mean;
  float sc = g[t] * rsqrtf(var + 1e-5f);
  float sh = be[t] - mean * sc;
  float v = y2[b * 512 + t] * sc + sh;
  v = v > 0.f ? v : 0.1f * v;
  red[t] = v * w[t];
  __syncthreads();
  if (t < 256) red[t] += red[t + 256];
  __syncthreads();
  if (t < 128) red[t] += red[t + 128];
  __syncthreads();
  if (t < 64) {
    float x = red[t] + red[t + 64];
    for (int off = 32; off; off >>= 1) x += __shfl_down(x, off);
    if (t == 0) out[b] = x + bias[0];
  }
}

extern "C" void kernel_launch(void* const* d_in, const int* in_sizes, int n_in,
                              void* d_out, int out_size, void* d_ws, size_t ws_size,
                              hipStream_t stream) {
  const int* adj = (const int*)d_in[0];
  const float* w0a = (const float*)d_in[1];
  const float* b0a = (const float*)d_in[2];
  const float* b0b = (const float*)d_in[4];
  const float* b1a = (const float*)d_in[6];
  const float* b1b = (const float*)d_in[8];
  const float* b2a = (const float*)d_in[10];
  const float* b2b = (const float*)d_in[12];
  const float* bn_in_g = (const float*)d_in[13];
  const float* bn_in_b = (const float*)d_in[14];
  const float* bn0_g = (const float*)d_in[15];
  const float* bn0_b = (const float*)d_in[16];
  const float* bn1_g = (const float*)d_in[17];
  const float* bn1_b = (const float*)d_in[18];
  const float* bn2_g = (const float*)d_in[19];
  const float* bn2_b = (const float*)d_in[20];
  const float* ln_g = (const float*)d_in[21];
  const float* ln_b = (const float*)d_in[22];
  const float* fc1_w = (const float*)d_in[23];
  const float* fc1_b = (const float*)d_in[24];
  const float* fcbn1_g = (const float*)d_in[25];
  const float* fcbn1_b = (const float*)d_in[26];
  const float* fc2_w = (const float*)d_in[27];
  const float* fc2_b = (const float*)d_in[28];
  const float* fcbn2_g = (const float*)d_in[29];
  const float* fcbn2_b = (const float*)d_in[30];
  const float* fc3_w = (const float*)d_in[31];
  const float* fc3_b = (const float*)d_in[32];

  char* ws = (char*)d_ws;
  size_t need = 122127360;
  if (ws_size < need) return;   // clean failure signature instead of OOB writes

  unsigned* Abits = (unsigned*)ws;                         // 16 MiB
  size_t off = 16777216;
  float* cnt = (float*)(ws + off); off += 2097152;
  unsigned short* h_rm = (unsigned short*)(ws + off); off += 33554432;
  unsigned short* h_t  = (unsigned short*)(ws + off); off += 33554432;
  unsigned short* mbuf = (unsigned short*)(ws + off); off += 33554432;
  unsigned short* wT = (unsigned short*)(ws + off); off += 163840;
  float* ps = (float*)(ws + off); off += 524288;
  float* pq = (float*)(ws + off); off += 524288;
  float* pool_ps = (float*)(ws + off); off += 524288;
  float* st = (float*)(ws + off); off += 1024;
  float* y1 = (float*)(ws + off); off += 131072;
  float* y2 = (float*)(ws + off); off += 262144;

  float* out = (float*)d_out;

  // pack (1024 blocks) + weight transpose (640 blocks) merged
  k_pack<<<dim3(1664), dim3(256), 0, stream>>>(adj, Abits, cnt,
      (const float*)d_in[3], (const float*)d_in[5], (const float*)d_in[7],
      (const float*)d_in[9], (const float*)d_in[11], wT);
  // layer 0 (fused): z0 closed form + GEMM(w0b) + stats
  k_layer0<<<dim3(1024), dim3(256), 0, stream>>>(cnt, w0a, b0a, bn_in_g, bn_in_b,
      wT + 0 * 16384, b0b, mbuf, ps, pq);
  k_bnred<<<dim3(128), dim3(256), 0, stream>>>(ps, pq, bn0_g, bn0_b, st);
  k_apply<<<dim3(1024), dim3(256), 0, stream>>>(mbuf, st, h_rm, h_t, pool_ps, 0, 1, 0);
  // layer 1 (fused)
  k_layer<<<dim3(1024), dim3(256), 0, stream>>>(Abits, h_t,
      wT + 1 * 16384, b1a, wT + 2 * 16384, b1b, mbuf, ps, pq);
  k_bnred<<<dim3(128), dim3(256), 0, stream>>>(ps, pq, bn1_g, bn1_b, st);
  k_apply<<<dim3(1024), dim3(256), 0, stream>>>(mbuf, st, h_rm, h_t, pool_ps, 1, 1, 0);
  // layer 2 (fused)
  k_layer<<<dim3(1024), dim3(256), 0, stream>>>(Abits, h_t,
      wT + 3 * 16384, b2a, wT + 4 * 16384, b2b, mbuf, ps, pq);
  k_bnred<<<dim3(128), dim3(256), 0, stream>>>(ps, pq, bn2_g, bn2_b, st);
  k_apply<<<dim3(1024), dim3(256), 0, stream>>>(mbuf, st, h_rm, h_t, pool_ps, 1, 0, 1);
  // head
  k_poolfc1<<<dim3(128), dim3(256), 0, stream>>>(pool_ps, ln_g, ln_b, fc1_w, fc1_b, y1);
  k_fc2bn<<<dim3(128), dim3(512), 0, stream>>>(y1, fcbn1_g, fcbn1_b, fc2_w, fc2_b, y2);
  k_fc3bn<<<dim3(128), dim3(512), 0, stream>>>(y2, fcbn2_g, fcbn2_b, fc3_w, fc3_b, out);
}

// Round 18
// 411.101 us; speedup vs baseline: 1.0698x; 1.0698x over previous
//
#include <hip/hip_runtime.h>
#include <hip/hip_bf16.h>

typedef float f32x4 __attribute__((ext_vector_type(4)));
typedef _Float16 half8 __attribute__((ext_vector_type(8)));
typedef _Float16 half4 __attribute__((ext_vector_type(4)));

__device__ __forceinline__ unsigned short f2h(float f) {
  return __builtin_bit_cast(unsigned short, (_Float16)f);   // RNE
}
__device__ __forceinline__ float h2f(unsigned short u) {
  return (float)__builtin_bit_cast(_Float16, u);
}
// expand low 2 bits -> packed pair of fp16 {1.0|0.0}  (bit-exact, integer mul)
__device__ __forceinline__ unsigned expand2(unsigned b2) {
  return ((b2 & 1u) | ((b2 & 2u) << 15)) * 0x3C00u;
}
// expand 8 bits -> 8 fp16 {1.0|0.0}
__device__ __forceinline__ half8 expand8(unsigned v) {
  uint4 u;
  u.x = expand2(v);
  u.y = expand2(v >> 2);
  u.z = expand2(v >> 4);
  u.w = expand2(v >> 6);
  return __builtin_bit_cast(half8, u);
}

// ---- pack adj -> bit-packed transposed Abits[b][i][j/32] + type counts.
//      Register bit-build: no input LDS tile, no barriers in main loop.
//      blocks >= 1024 do the weight transpose. ----
__global__ __launch_bounds__(256) void k_pack(const int* __restrict__ adj,
    unsigned* __restrict__ Abits, float* __restrict__ cnt,
    const float* __restrict__ w0b, const float* __restrict__ w1a,
    const float* __restrict__ w1b, const float* __restrict__ w2a,
    const float* __restrict__ w2b, unsigned short* __restrict__ wT) {
  __shared__ unsigned bitT[128 * 33];  // 16.9 KB
  __shared__ float cred[256 * 3];      // 3 KB
  int blk = blockIdx.x;
  if (blk >= 1024) {                   // weight transpose: 640 blocks
    int wb = blk - 1024;
    if (threadIdx.x < 128) {
      int mat = wb >> 7, k = wb & 127, dd = threadIdx.x;
      const float* src = (mat == 0) ? w0b : (mat == 1) ? w1a : (mat == 2) ? w1b
                        : (mat == 3) ? w2a : w2b;
      wT[mat * 16384 + dd * 128 + k] = f2h(src[k * 128 + dd]);
    }
    return;
  }
  int b = blk >> 3, i0 = (blk & 7) << 7;
  int t = threadIdx.x;
  int g = t >> 6;                      // wave id: one jt per wave per outer iter
  int u = t & 63, iq = u & 31, js = u >> 5;
  for (int o = 0; o < 4; ++o) {
    int jt = o * 4 + g;
    int jbase = jt << 6;
    unsigned b0 = 0, b1 = 0, b2 = 0, b3 = 0;
    for (int r = 0; r < 32; ++r) {
      int jl = js * 32 + r;
      int4 v = *reinterpret_cast<const int4*>(
          &adj[((size_t)b << 20) + ((size_t)(jbase + jl) << 10) + i0 + iq * 4]);
      b0 |= (unsigned)(v.x & 1) << r;
      b1 |= (unsigned)(v.y & 1) << r;
      b2 |= (unsigned)(v.z & 1) << r;
      b3 |= (unsigned)(v.w & 1) << r;
    }
    int base = (iq * 4) * 33 + jt * 2 + js;
    bitT[base] = b0;
    bitT[base + 33] = b1;
    bitT[base + 66] = b2;
    bitT[base + 99] = b3;
  }
  __syncthreads();
  // counts from bitT (bit-identical integers to direct counting)
  {
    int il = t & 127, half = t >> 7;
    float c0 = 0, c1 = 0, c2 = 0;
    for (int mi = 0; mi < 16; ++mi) {
      int m = half * 16 + mi;          // word index 0..31; jt = m>>1
      int pc = __popc(bitT[il * 33 + m]);
      if (half == 0) c0 += pc;         // m<16  -> j<512   (type 0)
      else if (m < 24) c1 += pc;       // jt 8..11 -> type 1
      else c2 += pc;                   // jt 12..15 -> type 2
    }
    cred[t * 3 + 0] = c0;
    cred[t * 3 + 1] = c1;
    cred[t * 3 + 2] = c2;
  }
  __syncthreads();
  if (t < 128) {
    for (int c = 0; c < 3; ++c)
      cnt[(((size_t)b << 10) + i0 + t) * 4 + c] = cred[t * 3 + c] + cred[(t + 128) * 3 + c];
  }
  unsigned* dst = Abits + ((size_t)b << 15) + ((size_t)i0 << 5);
  for (int q = 0; q < 16; ++q) {
    int f = t + 256 * q;
    dst[f] = bitT[(f >> 5) * 33 + (f & 31)];
  }
}

// ---- fused layer (layers 1,2): agg=h+A^T h -> z=leaky(agg@wa+ba) -> m=z@wb+bb
//      + BN partial stats. Residual from h_t (L2-hot). XCD-swizzled blockIdx. ----
__global__ __launch_bounds__(256) void k_layer(const unsigned* __restrict__ Abits,
    const unsigned short* __restrict__ h_t,
    const unsigned short* __restrict__ waT, const float* __restrict__ ba,
    const unsigned short* __restrict__ wbT, const float* __restrict__ bb,
    unsigned short* __restrict__ m_out, float* __restrict__ ps, float* __restrict__ pq) {
  __shared__ __align__(16) unsigned short smem[18432];   // 36.9 KB
  unsigned short* tb0 = smem;           // phase A: h_t tile buf0 [128][72]
  unsigned short* tb1 = smem + 9216;    // phase A: h_t tile buf1
  unsigned short* tz = smem;            // phase B: agg/z [128][136]
  int d = blockIdx.x;
  // XCD swizzle: all 8 subtiles of a graph land on the same XCD (bijective)
  int b = (d & 7) + ((d >> 6) << 3);
  int i0 = ((d >> 3) & 7) << 7;
  int t = threadIdx.x;
  int w = t >> 6, lane = t & 63;
  int wr = (w >> 1) * 64, wc = (w & 1) * 64;
  int lr = lane & 15, lk8 = (lane >> 4) * 8;
  const unsigned* Ab = Abits + ((size_t)b << 15);

  // ---- phase A: SpMM (A^T h), A from bit-expansion in registers ----
  f32x4 acc[4][4] = {};
  {
    for (int q = 0; q < 4; ++q) {
      int c = t * 4 + q;
      int r = c >> 3, off = (c & 7) << 3;
      *reinterpret_cast<uint4*>(&tb0[r * 72 + off]) =
        *reinterpret_cast<const uint4*>(&h_t[(((size_t)b << 7) + r) * 1024 + off]);
    }
  }
  __syncthreads();
  for (int jt = 0; jt < 16; ++jt) {
    unsigned short* cur = (jt & 1) ? tb1 : tb0;
    unsigned short* nxt = (jt & 1) ? tb0 : tb1;
    if (jt < 15) {
      for (int q = 0; q < 4; ++q) {
        int c = t * 4 + q;
        int r = c >> 3, off = (c & 7) << 3;
        *reinterpret_cast<uint4*>(&nxt[r * 72 + off]) =
          *reinterpret_cast<const uint4*>(&h_t[(((size_t)b << 7) + r) * 1024 + ((jt + 1) << 6) + off]);
      }
    }
    uint2 w01[4];
#pragma unroll
    for (int x = 0; x < 4; ++x)
      w01[x] = *reinterpret_cast<const uint2*>(&Ab[(i0 + wr + x * 16 + lr) * 32 + jt * 2]);
#pragma unroll
    for (int ks = 0; ks < 2; ++ks) {
      half8 bfr[4];
#pragma unroll
      for (int x = 0; x < 4; ++x)
        bfr[x] = *reinterpret_cast<const half8*>(&cur[(wc + x * 16 + lr) * 72 + ks * 32 + lk8]);
      half8 af[4];
#pragma unroll
      for (int x = 0; x < 4; ++x) {
        unsigned wk = ks ? w01[x].y : w01[x].x;
        af[x] = expand8(wk >> lk8);
      }
#pragma unroll
      for (int x = 0; x < 4; ++x)
#pragma unroll
        for (int y = 0; y < 4; ++y)
          acc[x][y] = __builtin_amdgcn_mfma_f32_16x16x32_f16(af[x], bfr[y], acc[x][y], 0, 0, 0);
    }
    __syncthreads();
  }
  // ---- residual add (from h_t, q-rows contiguous), agg -> tz (fp16) ----
  for (int x = 0; x < 4; ++x)
    for (int y = 0; y < 4; ++y) {
      int col = wc + y * 16 + lr;
      int row0 = wr + x * 16 + ((lane >> 4) << 2);
      uint2 rbits = *reinterpret_cast<const uint2*>(
          &h_t[((size_t)(b * 128 + col)) * 1024 + i0 + row0]);
      half4 rh = __builtin_bit_cast(half4, rbits);
      for (int q = 0; q < 4; ++q)
        tz[(row0 + q) * 136 + col] = f2h(acc[x][y][q] + (float)rh[q]);
    }
  __syncthreads();
  // ---- GEMM1: z = leaky(agg @ waT' + ba), weights direct from global ----
  f32x4 acc2[4][4] = {};
#pragma unroll
  for (int kt = 0; kt < 2; ++kt)
#pragma unroll
    for (int ks = 0; ks < 2; ++ks) {
      int k0 = kt * 64 + ks * 32 + lk8;
      half8 af[4], bw[4];
#pragma unroll
      for (int x = 0; x < 4; ++x)
        af[x] = *reinterpret_cast<const half8*>(&tz[(wr + x * 16 + lr) * 136 + k0]);
#pragma unroll
      for (int x = 0; x < 4; ++x)
        bw[x] = *reinterpret_cast<const half8*>(&waT[(wc + x * 16 + lr) * 128 + k0]);
#pragma unroll
      for (int x = 0; x < 4; ++x)
#pragma unroll
        for (int y = 0; y < 4; ++y)
          acc2[x][y] = __builtin_amdgcn_mfma_f32_16x16x32_f16(af[x], bw[y], acc2[x][y], 0, 0, 0);
    }
  __syncthreads();   // all GEMM1 tz reads done
  for (int x = 0; x < 4; ++x)
    for (int y = 0; y < 4; ++y)
      for (int q = 0; q < 4; ++q) {
        int row = wr + x * 16 + ((lane >> 4) << 2) + q;
        int col = wc + y * 16 + lr;
        float vv = acc2[x][y][q] + ba[col];
        vv = vv > 0.f ? vv : 0.1f * vv;
        tz[row * 136 + col] = f2h(vv);
      }
  __syncthreads();
  // ---- GEMM2: m = z @ wbT' + bb ----
  f32x4 acc3[4][4] = {};
#pragma unroll
  for (int kt = 0; kt < 2; ++kt)
#pragma unroll
    for (int ks = 0; ks < 2; ++ks) {
      int k0 = kt * 64 + ks * 32 + lk8;
      half8 af[4], bw[4];
#pragma unroll
      for (int x = 0; x < 4; ++x)
        af[x] = *reinterpret_cast<const half8*>(&tz[(wr + x * 16 + lr) * 136 + k0]);
#pragma unroll
      for (int x = 0; x < 4; ++x)
        bw[x] = *reinterpret_cast<const half8*>(&wbT[(wc + x * 16 + lr) * 128 + k0]);
#pragma unroll
      for (int x = 0; x < 4; ++x)
#pragma unroll
        for (int y = 0; y < 4; ++y)
          acc3[x][y] = __builtin_amdgcn_mfma_f32_16x16x32_f16(af[x], bw[y], acc3[x][y], 0, 0, 0);
    }
  // ---- epilogue: m write (fp16) + BN partial stats (on f32 values) ----
  float s[4] = {}, q2[4] = {};
  for (int x = 0; x < 4; ++x)
    for (int y = 0; y < 4; ++y)
      for (int q = 0; q < 4; ++q) {
        int row = wr + x * 16 + ((lane >> 4) << 2) + q;
        int col = wc + y * 16 + lr;
        float vv = acc3[x][y][q] + bb[col];
        m_out[(((size_t)b << 10) + i0 + row) * 128 + col] = f2h(vv);
        s[y] += vv; q2[y] += vv * vv;
      }
  __syncthreads();   // tz reads done before smem reuse as float
  float* fs = (float*)smem;          // [128][8]
  float* fq = fs + 1024;             // [128][8]
  int slot = (w >> 1) * 4 + (lane >> 4);
  for (int y = 0; y < 4; ++y) {
    int col = wc + y * 16 + lr;
    fs[col * 8 + slot] = s[y];
    fq[col * 8 + slot] = q2[y];
  }
  __syncthreads();
  if (t < 128) {
    float S = 0, Q = 0;
    for (int k = 0; k < 8; ++k) { S += fs[t * 8 + k]; Q += fq[t * 8 + k]; }
    ps[d * 128 + t] = S;
    pq[d * 128 + t] = Q;
  }
}

// ---- fused layer 0: z0 closed-form from counts -> m = z0 @ w0bT' + b0b + stats ----
__global__ __launch_bounds__(256) void k_layer0(const float* __restrict__ cnt,
    const float* __restrict__ w0a, const float* __restrict__ b0a,
    const float* __restrict__ g3, const float* __restrict__ bb3,
    const unsigned short* __restrict__ wbT, const float* __restrict__ bb,
    unsigned short* __restrict__ m_out, float* __restrict__ ps, float* __restrict__ pq) {
  __shared__ __align__(16) unsigned short smem[17408];
  unsigned short* tz = smem;            // [128][136]
  int blk = blockIdx.x;
  int b = blk >> 3, i0 = (blk & 7) << 7;
  int t = threadIdx.x;
  int w = t >> 6, lane = t & 63;
  int wr = (w >> 1) * 64, wc = (w & 1) * 64;
  int lr = lane & 15, lk8 = (lane >> 4) * 8;

  const float mean3[3] = {0.5f, 0.25f, 0.25f};
  const float var3[3] = {0.25f, 0.1875f, 0.1875f};
  float v[3][3];
  for (int c = 0; c < 3; ++c) {
    float rs = rsqrtf(var3[c] + 1e-5f) * g3[c];
    for (int tt = 0; tt < 3; ++tt)
      v[tt][c] = ((tt == c ? 1.f : 0.f) - mean3[c]) * rs + bb3[c];
  }
  int rr = t >> 1, hf = t & 1;
  int i = i0 + rr;
  int ty = i < 512 ? 0 : (i < 768 ? 1 : 2);
  const float* cc = cnt + (((size_t)b << 10) + i) * 4;
  float a0 = v[ty][0] + cc[0] * v[0][0] + cc[1] * v[1][0] + cc[2] * v[2][0];
  float a1 = v[ty][1] + cc[0] * v[0][1] + cc[1] * v[1][1] + cc[2] * v[2][1];
  float a2 = v[ty][2] + cc[0] * v[0][2] + cc[1] * v[1][2] + cc[2] * v[2][2];
  for (int c = 0; c < 64; ++c) {
    int col = hf * 64 + c;
    float z = a0 * w0a[col] + a1 * w0a[128 + col] + a2 * w0a[256 + col] + b0a[col];
    tz[rr * 136 + col] = f2h(fmaxf(z, 0.f));
  }
  __syncthreads();
  f32x4 acc3[4][4] = {};
#pragma unroll
  for (int kt = 0; kt < 2; ++kt)
#pragma unroll
    for (int ks = 0; ks < 2; ++ks) {
      int k0 = kt * 64 + ks * 32 + lk8;
      half8 af[4], bw[4];
#pragma unroll
      for (int x = 0; x < 4; ++x)
        af[x] = *reinterpret_cast<const half8*>(&tz[(wr + x * 16 + lr) * 136 + k0]);
#pragma unroll
      for (int x = 0; x < 4; ++x)
        bw[x] = *reinterpret_cast<const half8*>(&wbT[(wc + x * 16 + lr) * 128 + k0]);
#pragma unroll
      for (int x = 0; x < 4; ++x)
#pragma unroll
        for (int y = 0; y < 4; ++y)
          acc3[x][y] = __builtin_amdgcn_mfma_f32_16x16x32_f16(af[x], bw[y], acc3[x][y], 0, 0, 0);
    }
  float s[4] = {}, q2[4] = {};
  for (int x = 0; x < 4; ++x)
    for (int y = 0; y < 4; ++y)
      for (int q = 0; q < 4; ++q) {
        int row = wr + x * 16 + ((lane >> 4) << 2) + q;
        int col = wc + y * 16 + lr;
        float vv = acc3[x][y][q] + bb[col];
        m_out[(((size_t)b << 10) + i0 + row) * 128 + col] = f2h(vv);
        s[y] += vv; q2[y] += vv * vv;
      }
  __syncthreads();
  float* fs = (float*)smem;
  float* fq = fs + 1024;
  int slot = (w >> 1) * 4 + (lane >> 4);
  for (int y = 0; y < 4; ++y) {
    int col = wc + y * 16 + lr;
    fs[col * 8 + slot] = s[y];
    fq[col * 8 + slot] = q2[y];
  }
  __syncthreads();
  if (t < 128) {
    float S = 0, Q = 0;
    for (int k = 0; k < 8; ++k) { S += fs[t * 8 + k]; Q += fq[t * 8 + k]; }
    ps[blk * 128 + t] = S;
    pq[blk * 128 + t] = Q;
  }
}

// ---- BN stats final reduce: 128 blocks (one per channel) ----
__global__ __launch_bounds__(256) void k_bnred(const float* __restrict__ ps,
    const float* __restrict__ pq, const float* __restrict__ g,
    const float* __restrict__ be, float* __restrict__ st) {
  __shared__ float rs[4], rq[4];
  int ch = blockIdx.x, t = threadIdx.x;
  float s = 0, q = 0;
  for (int k = t; k < 1024; k += 256) {
    s += ps[k * 128 + ch]; q += pq[k * 128 + ch];
  }
  for (int off = 32; off; off >>= 1) {
    s += __shfl_down(s, off); q += __shfl_down(q, off);
  }
  if ((t & 63) == 0) { rs[t >> 6] = s; rq[t >> 6] = q; }
  __syncthreads();
  if (t == 0) {
    s = rs[0] + rs[1] + rs[2] + rs[3];
    q = rq[0] + rq[1] + rq[2] + rq[3];
    float mean = s * (1.f / 131072.f);
    float var = q * (1.f / 131072.f) - mean * mean;
    float sc = g[ch] * rsqrtf(var + 1e-5f);
    st[ch * 2] = sc;
    st[ch * 2 + 1] = be[ch] - mean * sc;
  }
}

// ---- BN apply + relu + residual; h row-major + transposed; optional pool partials ----
__global__ __launch_bounds__(256) void k_apply(const unsigned short* __restrict__ m,
    const float* __restrict__ st, unsigned short* __restrict__ h_rm,
    unsigned short* __restrict__ h_t, float* __restrict__ pool_ps,
    int use_res, int write_t, int do_pool) {
  __shared__ unsigned short lt[128 * 131];   // 33.5 KB (131: 2-way max bank alias)
  __shared__ float lp[128 * 16];             // 8 KB
  int blk = blockIdx.x;
  int b = blk >> 3, i0 = (blk & 7) << 7;
  int t = threadIdx.x;
  int chg = t & 15, rowg = t >> 4;
  int ch0 = chg * 8;
  float sc[8], sh[8];
#pragma unroll
  for (int j = 0; j < 8; ++j) { sc[j] = st[(ch0 + j) * 2]; sh[j] = st[(ch0 + j) * 2 + 1]; }
  float psum[8] = {};
  for (int it = 0; it < 8; ++it) {
    int row = it * 16 + rowg;
    size_t base = ((((size_t)b << 10) + i0 + row) << 7) + ch0;
    half8 mv = *reinterpret_cast<const half8*>(&m[base]);
    half8 rv{};
    if (use_res) rv = *reinterpret_cast<const half8*>(&h_rm[base]);
    half8 out;
#pragma unroll
    for (int j = 0; j < 8; ++j) {
      float vv = (float)mv[j] * sc[j] + sh[j];
      if (use_res) vv += (float)rv[j];
      vv = fmaxf(vv, 0.f);
      _Float16 hv = (_Float16)vv;
      out[j] = hv;
      psum[j] += (float)hv;
      lt[(ch0 + j) * 131 + row] = __builtin_bit_cast(unsigned short, hv);
    }
    if (write_t)   // h_rm only needed as next layer's residual source
      *reinterpret_cast<half8*>(&h_rm[base]) = out;
  }
  if (write_t) {
    __syncthreads();
    for (int it = 0; it < 16; ++it) {
      int ch2 = it * 8 + (t >> 5);
      int pu = (t & 31) * 4;
      unsigned u0 = lt[ch2 * 131 + pu];
      unsigned u1 = lt[ch2 * 131 + pu + 1];
      unsigned u2 = lt[ch2 * 131 + pu + 2];
      unsigned u3 = lt[ch2 * 131 + pu + 3];
      uint2 vv; vv.x = u0 | (u1 << 16); vv.y = u2 | (u3 << 16);
      *reinterpret_cast<uint2*>(&h_t[(((size_t)b << 7) + ch2) * 1024 + i0 + pu]) = vv;
    }
  }
  if (do_pool) {
#pragma unroll
    for (int j = 0; j < 8; ++j) lp[(ch0 + j) * 16 + rowg] = psum[j];
    __syncthreads();
    if (t < 128) {
      float S = 0;
      for (int k = 0; k < 16; ++k) S += lp[t * 16 + k];
      pool_ps[blk * 128 + t] = S;
    }
  }
}

// ---- pool merge + LayerNorm + fc1, fused (block = one graph) ----
__global__ __launch_bounds__(256) void k_poolfc1(const float* __restrict__ pool_ps,
    const float* __restrict__ ln_g, const float* __restrict__ ln_b,
    const float* __restrict__ w, const float* __restrict__ bias,
    float* __restrict__ y1) {
  __shared__ float ln[128];
  __shared__ float stat[2];
  int b = blockIdx.x, t = threadIdx.x;
  if (t < 128) {
    float s = 0;
    for (int k = 0; k < 8; ++k) s += pool_ps[((b << 3) + k) * 128 + t];
    ln[t] = s * (1.f / 1024.f);
  }
  __syncthreads();
  if (t < 64) {
    float a = ln[t], c = ln[t + 64];
    float ss = a + c, qq = a * a + c * c;
    for (int off = 32; off; off >>= 1) { ss += __shfl_down(ss, off); qq += __shfl_down(qq, off); }
    if (t == 0) {
      float mean = ss * (1.f / 128.f);
      float var = qq * (1.f / 128.f) - mean * mean;
      stat[0] = mean; stat[1] = rsqrtf(var + 1e-5f);
    }
  }
  __syncthreads();
  if (t < 128) ln[t] = (ln[t] - stat[0]) * stat[1] * ln_g[t] + ln_b[t];
  __syncthreads();
  float s = bias[t];
  for (int k = 0; k < 128; ++k) s += ln[k] * w[k * 256 + t];
  y1[b * 256 + t] = s;
}

// ---- bnhead1 + fc2 fused: each block recomputes stats (identical serial order) ----
__global__ __launch_bounds__(512) void k_fc2bn(const float* __restrict__ y1,
    const float* __restrict__ g, const float* __restrict__ be,
    const float* __restrict__ w, const float* __restrict__ bias,
    float* __restrict__ y2) {
  __shared__ float z1s[256];
  int b = blockIdx.x, t = threadIdx.x;
  if (t < 256) {
    float s = 0, q = 0;
    for (int bb = 0; bb < 128; ++bb) { float v = y1[bb * 256 + t]; s += v; q += v * v; }
    float mean = s * (1.f / 128.f);
    float var = q * (1.f / 128.f) - mean * mean;
    float sc = g[t] * rsqrtf(var + 1e-5f);
    float sh = be[t] - mean * sc;
    float v = y1[b * 256 + t] * sc + sh;
    z1s[t] = v > 0.f ? v : 0.1f * v;
  }
  __syncthreads();
  float s = bias[t];
  for (int k = 0; k < 256; ++k) s += z1s[k] * w[k * 512 + t];
  y2[b * 512 + t] = s;
}

// ---- bnhead2 + fc3 fused ----
__global__ __launch_bounds__(512) void k_fc3bn(const float* __restrict__ y2,
    const float* __restrict__ g, const float* __restrict__ be,
    const float* __restrict__ w, const float* __restrict__ bias,
    float* __restrict__ out) {
  __shared__ float red[512];
  int b = blockIdx.x, t = threadIdx.x;
  float s = 0, q = 0;
  for (int bb = 0; bb < 128; ++bb) { float v = y2[bb * 512 + t]; s += v; q += v * v; }
  float mean = s * (1.f / 128.f);
  float var = q * (1.f / 128.f) - mean * mean;
  float sc = g[t] * rsqrtf(var + 1e-5f);
  float sh = be[t] - mean * sc;
  float v = y2[b * 512 + t] * sc + sh;
  v = v > 0.f ? v : 0.1f * v;
  red[t] = v * w[t];
  __syncthreads();
  if (t < 256) red[t] += red[t + 256];
  __syncthreads();
  if (t < 128) red[t] += red[t + 128];
  __syncthreads();
  if (t < 64) {
    float x = red[t] + red[t + 64];
    for (int off = 32; off; off >>= 1) x += __shfl_down(x, off);
    if (t == 0) out[b] = x + bias[0];
  }
}

extern "C" void kernel_launch(void* const* d_in, const int* in_sizes, int n_in,
                              void* d_out, int out_size, void* d_ws, size_t ws_size,
                              hipStream_t stream) {
  const int* adj = (const int*)d_in[0];
  const float* w0a = (const float*)d_in[1];
  const float* b0a = (const float*)d_in[2];
  const float* b0b = (const float*)d_in[4];
  const float* b1a = (const float*)d_in[6];
  const float* b1b = (const float*)d_in[8];
  const float* b2a = (const float*)d_in[10];
  const float* b2b = (const float*)d_in[12];
  const float* bn_in_g = (const float*)d_in[13];
  const float* bn_in_b = (const float*)d_in[14];
  const float* bn0_g = (const float*)d_in[15];
  const float* bn0_b = (const float*)d_in[16];
  const float* bn1_g = (const float*)d_in[17];
  const float* bn1_b = (const float*)d_in[18];
  const float* bn2_g = (const float*)d_in[19];
  const float* bn2_b = (const float*)d_in[20];
  const float* ln_g = (const float*)d_in[21];
  const float* ln_b = (const float*)d_in[22];
  const float* fc1_w = (const float*)d_in[23];
  const float* fc1_b = (const float*)d_in[24];
  const float* fcbn1_g = (const float*)d_in[25];
  const float* fcbn1_b = (const float*)d_in[26];
  const float* fc2_w = (const float*)d_in[27];
  const float* fc2_b = (const float*)d_in[28];
  const float* fcbn2_g = (const float*)d_in[29];
  const float* fcbn2_b = (const float*)d_in[30];
  const float* fc3_w = (const float*)d_in[31];
  const float* fc3_b = (const float*)d_in[32];

  char* ws = (char*)d_ws;
  size_t need = 122127360;
  if (ws_size < need) return;   // clean failure signature instead of OOB writes

  unsigned* Abits = (unsigned*)ws;                         // 16 MiB
  size_t off = 16777216;
  float* cnt = (float*)(ws + off); off += 2097152;
  unsigned short* h_rm = (unsigned short*)(ws + off); off += 33554432;
  unsigned short* h_t  = (unsigned short*)(ws + off); off += 33554432;
  unsigned short* mbuf = (unsigned short*)(ws + off); off += 33554432;
  unsigned short* wT = (unsigned short*)(ws + off); off += 163840;
  float* ps = (float*)(ws + off); off += 524288;
  float* pq = (float*)(ws + off); off += 524288;
  float* pool_ps = (float*)(ws + off); off += 524288;
  float* st = (float*)(ws + off); off += 1024;
  float* y1 = (float*)(ws + off); off += 131072;
  float* y2 = (float*)(ws + off); off += 262144;

  float* out = (float*)d_out;

  // pack (1024 blocks) + weight transpose (640 blocks) merged
  k_pack<<<dim3(1664), dim3(256), 0, stream>>>(adj, Abits, cnt,
      (const float*)d_in[3], (const float*)d_in[5], (const float*)d_in[7],
      (const float*)d_in[9], (const float*)d_in[11], wT);
  // layer 0 (fused): z0 closed form + GEMM(w0b) + stats
  k_layer0<<<dim3(1024), dim3(256), 0, stream>>>(cnt, w0a, b0a, bn_in_g, bn_in_b,
      wT + 0 * 16384, b0b, mbuf, ps, pq);
  k_bnred<<<dim3(128), dim3(256), 0, stream>>>(ps, pq, bn0_g, bn0_b, st);
  k_apply<<<dim3(1024), dim3(256), 0, stream>>>(mbuf, st, h_rm, h_t, pool_ps, 0, 1, 0);
  // layer 1 (fused)
  k_layer<<<dim3(1024), dim3(256), 0, stream>>>(Abits, h_t,
      wT + 1 * 16384, b1a, wT + 2 * 16384, b1b, mbuf, ps, pq);
  k_bnred<<<dim3(128), dim3(256), 0, stream>>>(ps, pq, bn1_g, bn1_b, st);
  k_apply<<<dim3(1024), dim3(256), 0, stream>>>(mbuf, st, h_rm, h_t, pool_ps, 1, 1, 0);
  // layer 2 (fused)
  k_layer<<<dim3(1024), dim3(256), 0, stream>>>(Abits, h_t,
      wT + 3 * 16384, b2a, wT + 4 * 16384, b2b, mbuf, ps, pq);
  k_bnred<<<dim3(128), dim3(256), 0, stream>>>(ps, pq, bn2_g, bn2_b, st);
  k_apply<<<dim3(1024), dim3(256), 0, stream>>>(mbuf, st, h_rm, h_t, pool_ps, 1, 0, 1);
  // head
  k_poolfc1<<<dim3(128), dim3(256), 0, stream>>>(pool_ps, ln_g, ln_b, fc1_w, fc1_b, y1);
  k_fc2bn<<<dim3(128), dim3(512), 0, stream>>>(y1, fcbn1_g, fcbn1_b, fc2_w, fc2_b, y2);
  k_fc3bn<<<dim3(128), dim3(512), 0, stream>>>(y2, fcbn2_g, fcbn2_b, fc3_w, fc3_b, out);
}